// Round 1
// baseline (1693.357 us; speedup 1.0000x reference)
//
#include <hip/hip_runtime.h>
#include <math.h>

// Problem constants: NS=64 NG=3 W=128 L=1024 M=32 TD=64 CD=128 NB=4 B=256
// fr: (256,128,1024) f32 = 134 MB, updated in place across 4 FNO blocks.
// rfft/irfft with only 32 modes are implemented as dense DFT matmuls with
// precomputed trig tables (c2r convention: DC imag dropped, 2/L scaling).

__device__ __forceinline__ float gelu_f(float x){
  return 0.5f*x*(1.0f + erff(x*0.70710678118654752440f));
}

// ---------------- tables: POS (128x1024), Ftab (1024x64), G (64x1024) ----
__global__ void k_tables(float* __restrict__ POS, float* __restrict__ Ftab,
                         float* __restrict__ G){
  int idx = blockIdx.x*blockDim.x + threadIdx.x;
  if (idx < 32*1024){
    int k = idx >> 10, l = idx & 1023;
    int m = (k*l) & 1023;
    float s, c;
    sincospif((float)m*(1.0f/512.0f), &s, &c);     // angle = 2*pi*k*l/1024
    Ftab[l*64 + 2*k]   = c;                         // Re part of e^{-i t}
    Ftab[l*64 + 2*k+1] = -s;                        // Im part
    float sc = (k==0) ? (1.0f/1024.0f) : (2.0f/1024.0f);
    G[(2*k)*1024 + l]   = sc*c;
    G[(2*k+1)*1024 + l] = (k==0) ? 0.0f : -sc*s;    // DC imag ignored (c2r)
  }
  if (idx < 128*1024){
    int i = idx >> 10, l = idx & 1023;
    int j = i >> 1;
    float d = exp2f(-(float)j*(13.287712379549449f/64.0f)); // 10000^{-j/64}
    float ang = (float)l*d;
    POS[idx] = (i&1) ? cosf(ang) : sinf(ang);
  }
}

// ---------------- conditioning MLPs -> lifted (256x128) -----------------
__global__ __launch_bounds__(128) void k_cond(const float* __restrict__ x,
    const float* __restrict__ ts,
    const float* __restrict__ w1, const float* __restrict__ b1,
    const float* __restrict__ w2, const float* __restrict__ b2,
    const float* __restrict__ lw, const float* __restrict__ lb,
    float* __restrict__ lifted){
  const int b = blockIdx.x, t = threadIdx.x;
  __shared__ float sp[64], cin[68], h[128], cond[128];
  const float* xr = x + b*68;
  if (t < 64) sp[t] = xr[t];
  if (t < 3)  cin[t] = xr[64+t];
  if (t >= 64 && t < 96){
    int j = t - 64;
    float tt = xr[67]*ts[0];
    float invf = exp2f(-(float)j*(13.287712379549449f/31.0f)); // 1e4^{-j/31}
    float ang = tt*invf;
    cin[3+j]  = sinf(ang);
    cin[35+j] = cosf(ang);
  }
  __syncthreads();
  float acc = b1[t];
  for (int k = 0; k < 67; k++) acc += cin[k]*w1[t*67+k];
  h[t] = gelu_f(acc);
  __syncthreads();
  acc = b2[t];
  for (int k = 0; k < 128; k++) acc += h[k]*w2[t*128+k];
  cond[t] = acc;
  __syncthreads();
  acc = lb[t];
  const float* lwr = lw + t*192;
  for (int k = 0; k < 64; k++)  acc += sp[k]*lwr[k];
  for (int k = 0; k < 128; k++) acc += cond[k]*lwr[64+k];
  lifted[b*128 + t] = gelu_f(acc);
}

// ---------------- fr init: fr[b,i,l] = lifted[b,i] + POS[i,l] ----------
__global__ __launch_bounds__(256) void k_frinit(const float* __restrict__ lifted,
    const float* __restrict__ POS, float* __restrict__ fr){
  size_t idx = (size_t)blockIdx.x*256 + threadIdx.x;  // one float4 each
  size_t e = idx*4;
  int bi = (int)(e >> 10);
  int i  = bi & 127;
  int l  = (int)(e & 1023);
  float lf = lifted[bi];
  float4 p = *(const float4*)(POS + i*1024 + l);
  float4 o; o.x = lf+p.x; o.y = lf+p.y; o.z = lf+p.z; o.w = lf+p.w;
  *(float4*)(fr + e) = o;
}

// ---------------- DFT: ft(32768x64) = fr(32768x1024) @ Ftab(1024x64) ----
__global__ __launch_bounds__(256) void k_dft(const float* __restrict__ fr,
    const float* __restrict__ Ftab, float* __restrict__ ft){
  __shared__ float As[32][68];   // [kk][row], padded
  __shared__ float Bs[32][64];   // [kk][col]
  const int t = threadIdx.x;
  const int tx = t & 15, ty = t >> 4;
  const int bm = blockIdx.x;
  float acc[4][4] = {};
  const float* Ab = fr + (size_t)bm*64*1024;
  for (int k0 = 0; k0 < 1024; k0 += 32){
    {
      const int r = t>>3, c4 = (t&7)*4;
      float4 a0 = *(const float4*)(Ab + (size_t)r*1024 + k0 + c4);
      float4 a1 = *(const float4*)(Ab + (size_t)(r+32)*1024 + k0 + c4);
      As[c4+0][r] = a0.x; As[c4+1][r] = a0.y; As[c4+2][r] = a0.z; As[c4+3][r] = a0.w;
      As[c4+0][r+32] = a1.x; As[c4+1][r+32] = a1.y; As[c4+2][r+32] = a1.z; As[c4+3][r+32] = a1.w;
      const int cb = (t&7)*8;
      *(float4*)&Bs[r][cb]   = *(const float4*)(Ftab + (size_t)(k0+r)*64 + cb);
      *(float4*)&Bs[r][cb+4] = *(const float4*)(Ftab + (size_t)(k0+r)*64 + cb + 4);
    }
    __syncthreads();
    #pragma unroll
    for (int kk = 0; kk < 32; kk++){
      float4 a  = *(const float4*)&As[kk][ty*4];
      float4 bv = *(const float4*)&Bs[kk][tx*4];
      float av[4] = {a.x,a.y,a.z,a.w};
      float bb[4] = {bv.x,bv.y,bv.z,bv.w};
      #pragma unroll
      for (int j = 0; j < 4; j++)
        #pragma unroll
        for (int q = 0; q < 4; q++)
          acc[j][q] += av[j]*bb[q];
    }
    __syncthreads();
  }
  #pragma unroll
  for (int r = 0; r < 4; r++){
    float4 o = make_float4(acc[r][0], acc[r][1], acc[r][2], acc[r][3]);
    *(float4*)(ft + (size_t)(bm*64 + ty*4 + r)*64 + tx*4) = o;
  }
}

// ---------------- mode mix: out_ft[b,o,k] = sum_i ft[b,i,k]*wc[i,o,k] ----
__global__ __launch_bounds__(256) void k_modemm(const float* __restrict__ ft,
    const float* __restrict__ spec, float* __restrict__ oft){
  const int k = blockIdx.x;          // 0..31
  const int b0 = blockIdx.y*16;      // 16 b per block
  const int t = threadIdx.x;
  __shared__ float fA[128][32];      // [i][bl*2 + {re,im}]
  {
    const int bl = t & 15, i0 = (t>>4)*8;
    #pragma unroll
    for (int ii = 0; ii < 8; ii++){
      int i = i0 + ii;
      float2 v = *(const float2*)(ft + ((size_t)(b0+bl)*128 + i)*64 + 2*k);
      fA[i][bl*2]   = v.x;
      fA[i][bl*2+1] = v.y;
    }
  }
  __syncthreads();
  const int o = t & 127, bh = t >> 7;
  float accre[8] = {}, accim[8] = {};
  for (int i = 0; i < 128; i++){
    float2 w = *(const float2*)(spec + (((size_t)i*128 + o)*32 + k)*2);
    #pragma unroll
    for (int j = 0; j < 8; j++){
      float2 a = *(const float2*)&fA[i][(bh*8+j)*2];
      accre[j] += a.x*w.x - a.y*w.y;
      accim[j] += a.x*w.y + a.y*w.x;
    }
  }
  #pragma unroll
  for (int j = 0; j < 8; j++){
    float2 o2; o2.x = accre[j]; o2.y = accim[j];
    *(float2*)(oft + ((size_t)(b0+bh*8+j)*128 + o)*64 + 2*k) = o2;
  }
}

// ---------------- combine: y = irfft-part + conv + LN + gelu, in place --
// grid (32 ltiles, 256 b), 256 threads, per-thread 4o x 4l tile.
__global__ __launch_bounds__(256) void k_combine(float* __restrict__ fr,
    const float* __restrict__ oft,
    const float* __restrict__ cw, const float* __restrict__ cb,
    const float* __restrict__ g,  const float* __restrict__ bt,
    const float* __restrict__ G){
  const int l0 = blockIdx.x*32;
  const int b  = blockIdx.y;
  const int t  = threadIdx.x;
  const int tx = t & 7;      // l quad (8 -> 32 l)
  const int oty = t >> 3;    // o quad (32 -> 128 o)
  __shared__ float smem[12992];
  float* OsT = smem;             // [64][128]  (phase 1)
  float* frT = smem;             // [128][32]  (phase 2, reuse)
  float* ys  = smem + 4096;      // [128][33]
  float* Bb  = smem + 8320;      // Gt [64][32] then CWt [32][128]
  float* red1= smem + 12416;     // [8][32]
  float* red2= smem + 12672;     // [8][32]
  float* mu  = smem + 12928;     // [32]
  float* rs  = smem + 12960;     // [32]

  // P0: stage OsT (transposed out_ft row block) + Gt
  {
    const int o = t >> 1, half = t & 1;
    const float* src = oft + ((size_t)b*128 + o)*64 + half*32;
    #pragma unroll
    for (int q = 0; q < 8; q++){
      float4 v = *(const float4*)(src + q*4);
      int c = half*32 + q*4;
      OsT[(c+0)*128 + o] = v.x;  OsT[(c+1)*128 + o] = v.y;
      OsT[(c+2)*128 + o] = v.z;  OsT[(c+3)*128 + o] = v.w;
    }
    const int r = t >> 2, q4 = (t & 3)*8;
    *(float4*)&Bb[r*32 + q4]     = *(const float4*)(G + (size_t)r*1024 + l0 + q4);
    *(float4*)&Bb[r*32 + q4 + 4] = *(const float4*)(G + (size_t)r*1024 + l0 + q4 + 4);
  }
  __syncthreads();

  float acc[4][4] = {};
  // P1: x1 = OsT^T @ Gt  (K=64)
  #pragma unroll 8
  for (int kk = 0; kk < 64; kk++){
    float4 a  = *(const float4*)&OsT[kk*128 + oty*4];
    float4 bv = *(const float4*)&Bb[kk*32 + tx*4];
    float av[4] = {a.x,a.y,a.z,a.w};
    float bb[4] = {bv.x,bv.y,bv.z,bv.w};
    #pragma unroll
    for (int j = 0; j < 4; j++)
      #pragma unroll
      for (int q = 0; q < 4; q++)
        acc[j][q] += av[j]*bb[q];
  }
  __syncthreads();

  // P2: stage frT, then conv GEMM in 4 K-chunks of 32
  #pragma unroll
  for (int it = 0; it < 4; it++){
    const int r = it*32 + (t>>3), c4 = (t&7)*4;
    *(float4*)&frT[r*32 + c4] =
        *(const float4*)(fr + ((size_t)b*128 + r)*1024 + l0 + c4);
  }
  for (int c0 = 0; c0 < 128; c0 += 32){
    {
      const int o = t >> 1, h = t & 1;
      const float* src = cw + o*128 + c0 + h*16;
      #pragma unroll
      for (int q = 0; q < 4; q++){
        float4 v = *(const float4*)(src + q*4);
        int c = h*16 + q*4;
        Bb[(c+0)*128 + o] = v.x;  Bb[(c+1)*128 + o] = v.y;
        Bb[(c+2)*128 + o] = v.z;  Bb[(c+3)*128 + o] = v.w;
      }
    }
    __syncthreads();
    #pragma unroll 8
    for (int kk = 0; kk < 32; kk++){
      float4 a  = *(const float4*)&Bb[kk*128 + oty*4];
      float4 bv = *(const float4*)&frT[(c0+kk)*32 + tx*4];
      float av[4] = {a.x,a.y,a.z,a.w};
      float bb[4] = {bv.x,bv.y,bv.z,bv.w};
      #pragma unroll
      for (int j = 0; j < 4; j++)
        #pragma unroll
        for (int q = 0; q < 4; q++)
          acc[j][q] += av[j]*bb[q];
    }
    __syncthreads();
  }

  // P3: y -> LDS, LayerNorm stats over 128 channels per l
  #pragma unroll
  for (int j = 0; j < 4; j++){
    const int o = oty*4 + j;
    const float cbv = cb[o];
    #pragma unroll
    for (int q = 0; q < 4; q++)
      ys[o*33 + tx*4 + q] = acc[j][q] + cbv;
  }
  __syncthreads();
  {
    const int l = t & 31, gid = t >> 5;
    float s = 0.f, s2 = 0.f;
    #pragma unroll
    for (int oo = 0; oo < 16; oo++){
      float v = ys[(gid*16 + oo)*33 + l];
      s += v; s2 += v*v;
    }
    red1[gid*32 + l] = s; red2[gid*32 + l] = s2;
  }
  __syncthreads();
  if (t < 32){
    float s = 0.f, s2 = 0.f;
    #pragma unroll
    for (int gi = 0; gi < 8; gi++){ s += red1[gi*32+t]; s2 += red2[gi*32+t]; }
    float m = s*(1.0f/128.0f);
    float var = s2*(1.0f/128.0f) - m*m;
    mu[t] = m; rs[t] = rsqrtf(var + 1e-5f);
  }
  __syncthreads();
  // P4: normalize + gelu + in-place write
  #pragma unroll
  for (int j = 0; j < 4; j++){
    const int o = oty*4 + j;
    const float gv = g[o], bv = bt[o];
    float4 ov;
    const float* yrow = &ys[o*33 + tx*4];
    ov.x = gelu_f((yrow[0] - mu[tx*4+0])*rs[tx*4+0]*gv + bv);
    ov.y = gelu_f((yrow[1] - mu[tx*4+1])*rs[tx*4+1]*gv + bv);
    ov.z = gelu_f((yrow[2] - mu[tx*4+2])*rs[tx*4+2]*gv + bv);
    ov.w = gelu_f((yrow[3] - mu[tx*4+3])*rs[tx*4+3]*gv + bv);
    *(float4*)(fr + ((size_t)b*128 + o)*1024 + l0 + tx*4) = ov;
  }
}

// ---------------- out init: out = sp + b2 ------------------------------
__global__ void k_initout(const float* __restrict__ x,
    const float* __restrict__ b2, float* __restrict__ out){
  int idx = blockIdx.x*256 + threadIdx.x;
  if (idx < 256*64){
    int b = idx >> 6, o = idx & 63;
    out[idx] = x[b*68 + o] + b2[o];
  }
}

// ---------------- projection + mean over L -----------------------------
// grid (4 strips, 256 b): each block does 256 l's in 16 tiles of 16.
__global__ __launch_bounds__(256) void k_proj(const float* __restrict__ fr,
    const float* __restrict__ w1, const float* __restrict__ b1,
    const float* __restrict__ w2, float* __restrict__ out){
  const int strip = blockIdx.x, b = blockIdx.y;
  const int t = threadIdx.x;
  const int tx = t & 3, ty = t >> 2;   // ty = o (0..63)
  __shared__ float w1T[128*64];
  __shared__ float w2T[64*64];
  __shared__ float frT[128*16];
  __shared__ float h2s[64*16];
  {
    const int o = t >> 2, q = t & 3;
    const float* s1 = w1 + o*128 + q*32;
    for (int c = 0; c < 32; c++) w1T[(q*32+c)*64 + o] = s1[c];
    const float* s2 = w2 + o*64 + q*16;
    for (int c = 0; c < 16; c++) w2T[(q*16+c)*64 + o] = s2[c];
  }
  __syncthreads();
  float dacc = 0.f;
  const float b1v = b1[ty];
  for (int it = 0; it < 16; it++){
    const int l0 = strip*256 + it*16;
    {
      const int r = t >> 1, h = t & 1;
      const float* src = fr + ((size_t)b*128 + r)*1024 + l0 + h*8;
      *(float4*)&frT[r*16 + h*8]     = *(const float4*)(src);
      *(float4*)&frT[r*16 + h*8 + 4] = *(const float4*)(src + 4);
    }
    __syncthreads();
    float a1[4] = {b1v, b1v, b1v, b1v};
    #pragma unroll 8
    for (int kk = 0; kk < 128; kk++){
      float a  = w1T[kk*64 + ty];
      float4 bv = *(const float4*)&frT[kk*16 + tx*4];
      a1[0] += a*bv.x; a1[1] += a*bv.y; a1[2] += a*bv.z; a1[3] += a*bv.w;
    }
    h2s[ty*16 + tx*4+0] = gelu_f(a1[0]);
    h2s[ty*16 + tx*4+1] = gelu_f(a1[1]);
    h2s[ty*16 + tx*4+2] = gelu_f(a1[2]);
    h2s[ty*16 + tx*4+3] = gelu_f(a1[3]);
    __syncthreads();
    float o0 = 0.f, o1 = 0.f, o2 = 0.f, o3 = 0.f;
    #pragma unroll 8
    for (int kk = 0; kk < 64; kk++){
      float a  = w2T[kk*64 + ty];
      float4 bv = *(const float4*)&h2s[kk*16 + tx*4];
      o0 += a*bv.x; o1 += a*bv.y; o2 += a*bv.z; o3 += a*bv.w;
    }
    dacc += o0 + o1 + o2 + o3;
    __syncthreads();
  }
  dacc += __shfl_down(dacc, 1, 4);
  dacc += __shfl_down(dacc, 2, 4);
  if (tx == 0) atomicAdd(&out[b*64 + ty], dacc*(1.0f/1024.0f));
}

extern "C" void kernel_launch(void* const* d_in, const int* in_sizes, int n_in,
                              void* d_out, int out_size, void* d_ws, size_t ws_size,
                              hipStream_t stream){
  const float* x    = (const float*)d_in[0];
  const float* ts   = (const float*)d_in[1];
  const float* cw1  = (const float*)d_in[2];
  const float* cb1  = (const float*)d_in[3];
  const float* cw2  = (const float*)d_in[4];
  const float* cb2  = (const float*)d_in[5];
  const float* lw   = (const float*)d_in[6];
  const float* lb   = (const float*)d_in[7];
  const float* spec = (const float*)d_in[8];
  const float* conw = (const float*)d_in[9];
  const float* conb = (const float*)d_in[10];
  const float* lng  = (const float*)d_in[11];
  const float* lnb  = (const float*)d_in[12];
  const float* pw1  = (const float*)d_in[13];
  const float* pb1  = (const float*)d_in[14];
  const float* pw2  = (const float*)d_in[15];
  const float* pb2  = (const float*)d_in[16];

  float* ws   = (float*)d_ws;
  float* fr   = ws;                    // 33554432
  float* ft   = ws + 33554432;         // 2097152
  float* oft  = ws + 35651584;         // 2097152
  float* lift = ws + 37748736;         // 32768
  float* POS  = ws + 37781504;         // 131072
  float* Ftab = ws + 37912576;         // 65536
  float* G    = ws + 37978112;         // 65536  (total ~145 MiB)

  hipLaunchKernelGGL(k_tables, dim3(512), dim3(256), 0, stream, POS, Ftab, G);
  hipLaunchKernelGGL(k_cond, dim3(256), dim3(128), 0, stream,
                     x, ts, cw1, cb1, cw2, cb2, lw, lb, lift);
  hipLaunchKernelGGL(k_frinit, dim3(32768), dim3(256), 0, stream, lift, POS, fr);
  for (int nb = 0; nb < 4; nb++){
    hipLaunchKernelGGL(k_dft, dim3(512), dim3(256), 0, stream, fr, Ftab, ft);
    hipLaunchKernelGGL(k_modemm, dim3(32,16), dim3(256), 0, stream,
                       ft, spec + (size_t)nb*1048576, oft);
    hipLaunchKernelGGL(k_combine, dim3(32,256), dim3(256), 0, stream,
                       fr, oft, conw + nb*16384, conb + nb*128,
                       lng + nb*128, lnb + nb*128, G);
  }
  hipLaunchKernelGGL(k_initout, dim3(64), dim3(256), 0, stream, x, pb2, (float*)d_out);
  hipLaunchKernelGGL(k_proj, dim3(4,256), dim3(256), 0, stream,
                     fr, pw1, pb1, pw2, (float*)d_out);
}

// Round 2
// 840.633 us; speedup vs baseline: 2.0144x; 2.0144x over previous
//
#include <hip/hip_runtime.h>
#include <math.h>

// NS=64 NG=3 W=128 L=1024 M=32 TD=64 CD=128 NB=4 B=256
// fr stored bf16 [b][c][l]. DFT/irfft as dense bf16 MFMA matmuls with
// precomputed transposed trig tables. LN/softmax-free epilogues in fp32.

typedef unsigned short u16;
typedef unsigned int u32;
typedef __attribute__((ext_vector_type(8))) short bf16x8;
typedef __attribute__((ext_vector_type(4))) float f32x4;

#define MFMA(a,b,c) __builtin_amdgcn_mfma_f32_16x16x32_bf16((a),(b),(c),0,0,0)

__device__ __forceinline__ float gelu_f(float x){
  return 0.5f*x*(1.0f + erff(x*0.70710678118654752440f));
}
__device__ __forceinline__ u16 f2bf(float f){
  u32 u = __float_as_uint(f);
  u32 r = (u + 0x7FFFu + ((u>>16)&1u)) >> 16;
  return (u16)r;
}
__device__ __forceinline__ int SW3(int x){ return ((x&7) ^ ((x>>4)&7)); }  // 128/256B rows
__device__ __forceinline__ int SWQ(int q){ return ((q&7) ^ ((q>>3)&7)); }  // 1024B rows

// ---- tables: POS f32(128x1024); FtabT bf16(64q x 1024l); GT bf16(1024l x 64q);
//      cwb bf16(4x128x128); w1b bf16(64x128); w2b bf16(64x64) ----
__global__ void k_tables(float* __restrict__ POS, u16* __restrict__ FtabT,
                         u16* __restrict__ GT, const float* __restrict__ conw,
                         u16* __restrict__ cwb, const float* __restrict__ pw1,
                         u16* __restrict__ w1b, const float* __restrict__ pw2,
                         u16* __restrict__ w2b){
  int idx = blockIdx.x*blockDim.x + threadIdx.x;
  if (idx < 128*1024){
    int i = idx >> 10, l = idx & 1023;
    int j = i >> 1;
    float d = exp2f(-(float)j*(13.287712379549449f/64.0f));
    float ang = (float)l*d;
    POS[idx] = (i&1) ? cosf(ang) : sinf(ang);
  }
  if (idx < 64*1024){
    int q = idx >> 10, l = idx & 1023;
    int k = q >> 1;
    int m = (k*l) & 1023;
    float s, c;
    sincospif((float)m*(1.0f/512.0f), &s, &c);
    FtabT[q*1024 + l] = f2bf((q&1) ? -s : c);
  }
  if (idx < 64*1024){
    int l = idx >> 6, q = idx & 63;
    int k = q >> 1;
    int m = (k*l) & 1023;
    float s, c;
    sincospif((float)m*(1.0f/512.0f), &s, &c);
    float sc = (k==0) ? (1.0f/1024.0f) : (2.0f/1024.0f);
    float v = (q&1) ? ((k==0) ? 0.0f : -sc*s) : sc*c;
    GT[l*64 + q] = f2bf(v);
  }
  if (idx < 4*128*128) cwb[idx] = f2bf(conw[idx]);
  if (idx < 64*128)    w1b[idx] = f2bf(pw1[idx]);
  if (idx < 64*64)     w2b[idx] = f2bf(pw2[idx]);
}

// ---- conditioning MLPs -> lifted (256x128) f32 ----
__global__ __launch_bounds__(128) void k_cond(const float* __restrict__ x,
    const float* __restrict__ ts,
    const float* __restrict__ w1, const float* __restrict__ b1,
    const float* __restrict__ w2, const float* __restrict__ b2,
    const float* __restrict__ lw, const float* __restrict__ lb,
    float* __restrict__ lifted){
  const int b = blockIdx.x, t = threadIdx.x;
  __shared__ float sp[64], cin[68], h[128], cond[128];
  const float* xr = x + b*68;
  if (t < 64) sp[t] = xr[t];
  if (t < 3)  cin[t] = xr[64+t];
  if (t >= 64 && t < 96){
    int j = t - 64;
    float tt = xr[67]*ts[0];
    float invf = exp2f(-(float)j*(13.287712379549449f/31.0f));
    float ang = tt*invf;
    cin[3+j]  = sinf(ang);
    cin[35+j] = cosf(ang);
  }
  __syncthreads();
  float acc = b1[t];
  for (int k = 0; k < 67; k++) acc += cin[k]*w1[t*67+k];
  h[t] = gelu_f(acc);
  __syncthreads();
  acc = b2[t];
  for (int k = 0; k < 128; k++) acc += h[k]*w2[t*128+k];
  cond[t] = acc;
  __syncthreads();
  acc = lb[t];
  const float* lwr = lw + t*192;
  for (int k = 0; k < 64; k++)  acc += sp[k]*lwr[k];
  for (int k = 0; k < 128; k++) acc += cond[k]*lwr[64+k];
  lifted[b*128 + t] = gelu_f(acc);
}

// ---- fr init (bf16): fr[b,c,l] = lifted[b,c] + POS[c,l] ----
__global__ __launch_bounds__(256) void k_frinit(const float* __restrict__ lifted,
    const float* __restrict__ POS, u16* __restrict__ fr){
  size_t idx = (size_t)blockIdx.x*256 + threadIdx.x;
  size_t e = idx*8;
  int bi = (int)(e >> 10);
  int l  = (int)(e & 1023);
  float lf = lifted[bi];
  const float* p = POS + (size_t)(bi & 127)*1024 + l;
  float4 p0 = *(const float4*)p;
  float4 p1 = *(const float4*)(p+4);
  u32 o0 = (u32)f2bf(lf+p0.x) | ((u32)f2bf(lf+p0.y)<<16);
  u32 o1 = (u32)f2bf(lf+p0.z) | ((u32)f2bf(lf+p0.w)<<16);
  u32 o2 = (u32)f2bf(lf+p1.x) | ((u32)f2bf(lf+p1.y)<<16);
  u32 o3 = (u32)f2bf(lf+p1.z) | ((u32)f2bf(lf+p1.w)<<16);
  *(uint4*)(fr + e) = make_uint4(o0,o1,o2,o3);
}

// ---- DFT: ft(32768x64 f32) = fr(32768x1024 bf16) @ FtabT^T, MFMA ----
// D[q][rows]: A = FtabT (LDS, swizzled), B = fr (global). 512 blocks x 64 rows.
__global__ __launch_bounds__(256) void k_dft(const u16* __restrict__ fr,
    const u16* __restrict__ FtabT, float* __restrict__ ft){
  const int t = threadIdx.x, w = t >> 6, lane = t & 63;
  const int nlo = lane & 15, kg = lane >> 4;
  const int row0 = blockIdx.x * 64;
  __shared__ u16 Fs[64*512];   // 64KB: [64 q][512 l] per half, swizzled
  f32x4 acc[4] = {};
  for (int h = 0; h < 2; ++h){
    #pragma unroll
    for (int r = 0; r < 16; ++r){
      int idx = r*256 + t;
      int q = idx >> 6, c64 = idx & 63;
      uint4 v = *(const uint4*)((const char*)FtabT + (size_t)q*2048 + h*1024 + c64*16);
      *(uint4*)((char*)Fs + q*1024 + ((c64 ^ SWQ(q))*16)) = v;
    }
    __syncthreads();
    for (int ks = 0; ks < 8; ++ks){
      const u16* frow = fr + (size_t)(row0 + w*16 + nlo)*1024 + h*512 + ks*64;
      bf16x8 b0 = *(const bf16x8*)(frow + kg*8);
      bf16x8 b1 = *(const bf16x8*)(frow + 32 + kg*8);
      #pragma unroll
      for (int mf = 0; mf < 4; ++mf){
        int q = mf*16 + nlo;
        const char* qrow = (const char*)Fs + q*1024;
        bf16x8 a0 = *(const bf16x8*)(qrow + (((ks*8 + kg) ^ SWQ(q))*16));
        bf16x8 a1 = *(const bf16x8*)(qrow + (((ks*8 + 4 + kg) ^ SWQ(q))*16));
        acc[mf] = MFMA(a0, b0, acc[mf]);
        acc[mf] = MFMA(a1, b1, acc[mf]);
      }
    }
    __syncthreads();
  }
  #pragma unroll
  for (int mf = 0; mf < 4; ++mf){
    float4 o = make_float4(acc[mf][0], acc[mf][1], acc[mf][2], acc[mf][3]);
    *(float4*)(ft + (size_t)(row0 + w*16 + nlo)*64 + mf*16 + kg*4) = o;
  }
}

// ---- mode mix (fp32 VALU), writes oft bf16 [b][o][64q] ----
__global__ __launch_bounds__(256) void k_modemm(const float* __restrict__ ft,
    const float* __restrict__ spec, u16* __restrict__ oftb){
  const int k = blockIdx.x;
  const int b0 = blockIdx.y*16;
  const int t = threadIdx.x;
  __shared__ float fA[128][32];
  {
    const int bl = t & 15, i0 = (t>>4)*8;
    #pragma unroll
    for (int ii = 0; ii < 8; ii++){
      int i = i0 + ii;
      float2 v = *(const float2*)(ft + ((size_t)(b0+bl)*128 + i)*64 + 2*k);
      fA[i][bl*2]   = v.x;
      fA[i][bl*2+1] = v.y;
    }
  }
  __syncthreads();
  const int o = t & 127, bh = t >> 7;
  float accre[8] = {}, accim[8] = {};
  for (int i = 0; i < 128; i++){
    float2 wv = *(const float2*)(spec + (((size_t)i*128 + o)*32 + k)*2);
    #pragma unroll
    for (int j = 0; j < 8; j++){
      float2 a = *(const float2*)&fA[i][(bh*8+j)*2];
      accre[j] += a.x*wv.x - a.y*wv.y;
      accim[j] += a.x*wv.y + a.y*wv.x;
    }
  }
  #pragma unroll
  for (int j = 0; j < 8; j++){
    u32 pk = (u32)f2bf(accre[j]) | ((u32)f2bf(accim[j])<<16);
    *(u32*)(oftb + ((size_t)(b0+bh*8+j)*128 + o)*64 + 2*k) = pk;
  }
}

// ---- combine: y = irfft(oft) + conv(fr) + cb; LN over o; gelu; fr in-place ----
// grid (16 ltiles, 256 b), 256 thr = 4 waves. D[l][o]: wave w: o-range w*32.
__global__ __launch_bounds__(256) void k_combine(u16* __restrict__ fr,
    const u16* __restrict__ oftb, const u16* __restrict__ cwb,
    const float* __restrict__ cb, const float* __restrict__ g,
    const float* __restrict__ bt, const u16* __restrict__ GT){
  const int l0 = blockIdx.x*64, b = blockIdx.y;
  const int t = threadIdx.x, w = t >> 6, lane = t & 63;
  const int nlo = lane & 15, kg = lane >> 4;
  __shared__ u16 frT[64*128];      // 16KB [l][c] swizzled (256B rows)
  __shared__ u16 GTs[64*64];       // 8KB  [l][q] swizzled (128B rows)
  __shared__ u16 ys[128*64];       // 16KB [o][l] swizzled (128B rows)
  __shared__ float red[4][64][2];
  __shared__ float stats[64][2];

  // stage GT tile (reg-staged, swizzle on LDS write)
  #pragma unroll
  for (int r = 0; r < 2; ++r){
    int idx = r*256 + t;
    int l = idx >> 3, c8 = idx & 7;
    uint4 v = *(const uint4*)((const char*)GT + (size_t)(l0+l)*128 + c8*16);
    *(uint4*)((char*)GTs + l*128 + ((c8 ^ SW3(l))*16)) = v;
  }
  // transpose-stage fr tile -> frT[l][c]
  {
    int p = t >> 2, q2 = t & 3;            // c-pair 0..63, l-quarter
    const u16* r0 = fr + ((size_t)b*128 + 2*p)*1024 + l0 + q2*16;
    uint4 A0 = *(const uint4*)r0;
    uint4 A1 = *(const uint4*)(r0 + 8);
    uint4 B0 = *(const uint4*)(r0 + 1024);
    uint4 B1 = *(const uint4*)(r0 + 1032);
    u32 wa[8] = {A0.x,A0.y,A0.z,A0.w,A1.x,A1.y,A1.z,A1.w};
    u32 wb[8] = {B0.x,B0.y,B0.z,B0.w,B1.x,B1.y,B1.z,B1.w};
    #pragma unroll
    for (int j = 0; j < 16; ++j){
      u32 ua = wa[j>>1], ub = wb[j>>1];
      u32 out = (j&1) ? ((ua>>16) | (ub & 0xffff0000u))
                      : ((ua & 0xffffu) | (ub<<16));
      int l = q2*16 + j;
      *(u32*)((char*)frT + l*256 + (((p>>2) ^ SW3(l))*16) + (p&3)*4) = out;
    }
  }
  __syncthreads();

  f32x4 acc[4][2] = {};
  // K-part 1: irfft basis (q = 0..63)
  #pragma unroll
  for (int ki = 0; ki < 2; ++ki){
    int q0 = ki*32;
    bf16x8 bfr[2];
    #pragma unroll
    for (int nf = 0; nf < 2; ++nf){
      int o = w*32 + nf*16 + nlo;
      bfr[nf] = *(const bf16x8*)(oftb + ((size_t)b*128 + o)*64 + q0 + kg*8);
    }
    #pragma unroll
    for (int mf = 0; mf < 4; ++mf){
      int l = mf*16 + nlo;
      bf16x8 af = *(const bf16x8*)((const char*)GTs + l*128 + (((q0/8 + kg) ^ SW3(l))*16));
      acc[mf][0] = MFMA(af, bfr[0], acc[mf][0]);
      acc[mf][1] = MFMA(af, bfr[1], acc[mf][1]);
    }
  }
  // K-part 2: conv (c = 0..127)
  #pragma unroll
  for (int ki = 0; ki < 4; ++ki){
    int c0 = ki*32;
    bf16x8 bfr[2];
    #pragma unroll
    for (int nf = 0; nf < 2; ++nf){
      int o = w*32 + nf*16 + nlo;
      bfr[nf] = *(const bf16x8*)(cwb + o*128 + c0 + kg*8);
    }
    #pragma unroll
    for (int mf = 0; mf < 4; ++mf){
      int l = mf*16 + nlo;
      bf16x8 af = *(const bf16x8*)((const char*)frT + l*256 + (((c0/8 + kg) ^ SW3(l))*16));
      acc[mf][0] = MFMA(af, bfr[0], acc[mf][0]);
      acc[mf][1] = MFMA(af, bfr[1], acc[mf][1]);
    }
  }

  // bias + LN stats
  float cbv[2], gv[2], btv[2];
  #pragma unroll
  for (int nf = 0; nf < 2; ++nf){
    int o = w*32 + nf*16 + nlo;
    cbv[nf] = cb[o]; gv[nf] = g[o]; btv[nf] = bt[o];
  }
  #pragma unroll
  for (int mf = 0; mf < 4; ++mf)
    #pragma unroll
    for (int nf = 0; nf < 2; ++nf)
      #pragma unroll
      for (int r = 0; r < 4; ++r)
        acc[mf][nf][r] += cbv[nf];

  float s[4][4], s2[4][4];
  #pragma unroll
  for (int mf = 0; mf < 4; ++mf)
    #pragma unroll
    for (int r = 0; r < 4; ++r){
      float a0 = acc[mf][0][r], a1 = acc[mf][1][r];
      s[mf][r] = a0 + a1;
      s2[mf][r] = a0*a0 + a1*a1;
    }
  #pragma unroll
  for (int m = 1; m <= 8; m <<= 1){
    #pragma unroll
    for (int mf = 0; mf < 4; ++mf)
      #pragma unroll
      for (int r = 0; r < 4; ++r){
        s[mf][r]  += __shfl_xor(s[mf][r], m);
        s2[mf][r] += __shfl_xor(s2[mf][r], m);
      }
  }
  if (nlo == 0){
    #pragma unroll
    for (int mf = 0; mf < 4; ++mf)
      #pragma unroll
      for (int r = 0; r < 4; ++r){
        int l = mf*16 + kg*4 + r;
        red[w][l][0] = s[mf][r];
        red[w][l][1] = s2[mf][r];
      }
  }
  __syncthreads();
  if (t < 64){
    float ss  = red[0][t][0]+red[1][t][0]+red[2][t][0]+red[3][t][0];
    float ss2 = red[0][t][1]+red[1][t][1]+red[2][t][1]+red[3][t][1];
    float mu = ss*(1.0f/128.0f);
    float var = ss2*(1.0f/128.0f) - mu*mu;
    stats[t][0] = mu;
    stats[t][1] = rsqrtf(var + 1e-5f);
  }
  __syncthreads();

  // normalize + gelu + pack to ys[o][l]
  #pragma unroll
  for (int mf = 0; mf < 4; ++mf){
    float2 st[4];
    #pragma unroll
    for (int r = 0; r < 4; ++r)
      st[r] = *(const float2*)&stats[mf*16 + kg*4 + r][0];
    #pragma unroll
    for (int nf = 0; nf < 2; ++nf){
      float vs[4];
      #pragma unroll
      for (int r = 0; r < 4; ++r){
        float v = (acc[mf][nf][r] - st[r].x)*st[r].y*gv[nf] + btv[nf];
        vs[r] = gelu_f(v);
      }
      u32 u01 = (u32)f2bf(vs[0]) | ((u32)f2bf(vs[1])<<16);
      u32 u23 = (u32)f2bf(vs[2]) | ((u32)f2bf(vs[3])<<16);
      int o = w*32 + nf*16 + nlo;
      int byteoff = o*128 + (((mf*2 + (kg>>1)) ^ SW3(o))*16) + (kg&1)*8;
      *(uint2*)((char*)ys + byteoff) = make_uint2(u01, u23);
    }
  }
  __syncthreads();
  // coalesced fr writeback
  {
    int o = t >> 1, half = t & 1;
    const char* base = (const char*)ys + o*128;
    u16* dst = fr + ((size_t)b*128 + o)*1024 + l0 + half*32;
    #pragma unroll
    for (int j = 0; j < 4; ++j){
      int chunk = half*4 + j;
      uint4 v = *(const uint4*)(base + ((chunk ^ SW3(o))*16));
      *(uint4*)(dst + j*8) = v;
    }
  }
}

// ---- out init: out = sp + proj_b2 ----
__global__ void k_initout(const float* __restrict__ x,
    const float* __restrict__ b2, float* __restrict__ out){
  int idx = blockIdx.x*256 + threadIdx.x;
  if (idx < 256*64){
    int b = idx >> 6, o = idx & 63;
    out[idx] = x[b*68 + o] + b2[o];
  }
}

// ---- projection (MFMA) + mean over L ----
__global__ __launch_bounds__(256) void k_proj(const u16* __restrict__ fr,
    const u16* __restrict__ w1b, const float* __restrict__ pb1,
    const u16* __restrict__ w2b, float* __restrict__ out){
  const int l0 = blockIdx.x*64, b = blockIdx.y;
  const int t = threadIdx.x, w = t >> 6, lane = t & 63;
  const int nlo = lane & 15, kg = lane >> 4;
  __shared__ u16 frT[64*128];   // 16KB [l][c] swizzled
  __shared__ u16 h2T[64*64];    // 8KB  [l][h] swizzled

  {
    int p = t >> 2, q2 = t & 3;
    const u16* r0 = fr + ((size_t)b*128 + 2*p)*1024 + l0 + q2*16;
    uint4 A0 = *(const uint4*)r0;
    uint4 A1 = *(const uint4*)(r0 + 8);
    uint4 B0 = *(const uint4*)(r0 + 1024);
    uint4 B1 = *(const uint4*)(r0 + 1032);
    u32 wa[8] = {A0.x,A0.y,A0.z,A0.w,A1.x,A1.y,A1.z,A1.w};
    u32 wb[8] = {B0.x,B0.y,B0.z,B0.w,B1.x,B1.y,B1.z,B1.w};
    #pragma unroll
    for (int j = 0; j < 16; ++j){
      u32 ua = wa[j>>1], ub = wb[j>>1];
      u32 o32 = (j&1) ? ((ua>>16) | (ub & 0xffff0000u))
                      : ((ua & 0xffffu) | (ub<<16));
      int l = q2*16 + j;
      *(u32*)((char*)frT + l*256 + (((p>>2) ^ SW3(l))*16) + (p&3)*4) = o32;
    }
  }
  __syncthreads();

  // GEMM1: h2[l][h] = gelu(fr^T @ w1^T + b1), wave w: h-range w*16
  f32x4 acc1[4] = {};
  #pragma unroll
  for (int ki = 0; ki < 4; ++ki){
    int c0 = ki*32;
    bf16x8 bfr = *(const bf16x8*)(w1b + (w*16 + nlo)*128 + c0 + kg*8);
    #pragma unroll
    for (int mf = 0; mf < 4; ++mf){
      int l = mf*16 + nlo;
      bf16x8 af = *(const bf16x8*)((const char*)frT + l*256 + (((c0/8 + kg) ^ SW3(l))*16));
      acc1[mf] = MFMA(af, bfr, acc1[mf]);
    }
  }
  float b1v = pb1[w*16 + nlo];
  #pragma unroll
  for (int mf = 0; mf < 4; ++mf){
    float vs[4];
    #pragma unroll
    for (int r = 0; r < 4; ++r) vs[r] = gelu_f(acc1[mf][r] + b1v);
    u32 w01 = (u32)f2bf(vs[0]) | ((u32)f2bf(vs[1])<<16);
    u32 w23 = (u32)f2bf(vs[2]) | ((u32)f2bf(vs[3])<<16);
    u32 p01 = __shfl_xor(w01, 1), p23 = __shfl_xor(w23, 1);
    int h = w*16 + nlo, hp = h >> 1;
    u32 outA, outB; int rA, rB;
    if (!(h & 1)){
      outA = (w01 & 0xffffu) | (p01 << 16); rA = 0;
      outB = (w01 >> 16) | (p01 & 0xffff0000u); rB = 1;
    } else {
      outA = (p23 & 0xffffu) | (w23 << 16); rA = 2;
      outB = (p23 >> 16) | (w23 & 0xffff0000u); rB = 3;
    }
    int lA = mf*16 + kg*4 + rA, lB = mf*16 + kg*4 + rB;
    *(u32*)((char*)h2T + lA*128 + (((hp>>2) ^ SW3(lA))*16) + (hp&3)*4) = outA;
    *(u32*)((char*)h2T + lB*128 + (((hp>>2) ^ SW3(lB))*16) + (hp&3)*4) = outB;
  }
  __syncthreads();

  // GEMM2: out[l][o] = h2 @ w2^T, wave w: o-range w*16; then mean over l
  f32x4 acc2[4] = {};
  #pragma unroll
  for (int ki = 0; ki < 2; ++ki){
    int h0 = ki*32;
    bf16x8 bfr = *(const bf16x8*)(w2b + (w*16 + nlo)*64 + h0 + kg*8);
    #pragma unroll
    for (int mf = 0; mf < 4; ++mf){
      int l = mf*16 + nlo;
      bf16x8 af = *(const bf16x8*)((const char*)h2T + l*128 + (((h0/8 + kg) ^ SW3(l))*16));
      acc2[mf] = MFMA(af, bfr, acc2[mf]);
    }
  }
  float ssum = 0.0f;
  #pragma unroll
  for (int mf = 0; mf < 4; ++mf)
    #pragma unroll
    for (int r = 0; r < 4; ++r) ssum += acc2[mf][r];
  ssum += __shfl_xor(ssum, 16);
  ssum += __shfl_xor(ssum, 32);
  if (kg == 0) atomicAdd(out + (size_t)b*64 + w*16 + nlo, ssum*(1.0f/1024.0f));
}

extern "C" void kernel_launch(void* const* d_in, const int* in_sizes, int n_in,
                              void* d_out, int out_size, void* d_ws, size_t ws_size,
                              hipStream_t stream){
  const float* x    = (const float*)d_in[0];
  const float* ts   = (const float*)d_in[1];
  const float* cw1  = (const float*)d_in[2];
  const float* cb1  = (const float*)d_in[3];
  const float* cw2  = (const float*)d_in[4];
  const float* cb2  = (const float*)d_in[5];
  const float* lw   = (const float*)d_in[6];
  const float* lb   = (const float*)d_in[7];
  const float* spec = (const float*)d_in[8];
  const float* conw = (const float*)d_in[9];
  const float* conb = (const float*)d_in[10];
  const float* lng  = (const float*)d_in[11];
  const float* lnb  = (const float*)d_in[12];
  const float* pw1  = (const float*)d_in[13];
  const float* pb1  = (const float*)d_in[14];
  const float* pw2  = (const float*)d_in[15];
  const float* pb2  = (const float*)d_in[16];

  char* W = (char*)d_ws;
  u16*   fr     = (u16*)  (W);                    // 67,108,864 B
  float* ft     = (float*)(W + 67108864);         //  8,388,608 B
  u16*   oftb   = (u16*)  (W + 75497472);         //  4,194,304 B
  float* lifted = (float*)(W + 79691776);         //    131,072 B
  float* POS    = (float*)(W + 79822848);         //    524,288 B
  u16*   FtabT  = (u16*)  (W + 80347136);         //    131,072 B
  u16*   GT     = (u16*)  (W + 80478208);         //    131,072 B
  u16*   cwb    = (u16*)  (W + 80609280);         //    131,072 B
  u16*   w1b    = (u16*)  (W + 80740352);         //     16,384 B
  u16*   w2b    = (u16*)  (W + 80756736);         //      8,192 B

  hipLaunchKernelGGL(k_tables, dim3(512), dim3(256), 0, stream,
                     POS, FtabT, GT, conw, cwb, pw1, w1b, pw2, w2b);
  hipLaunchKernelGGL(k_cond, dim3(256), dim3(128), 0, stream,
                     x, ts, cw1, cb1, cw2, cb2, lw, lb, lifted);
  hipLaunchKernelGGL(k_frinit, dim3(16384), dim3(256), 0, stream, lifted, POS, fr);
  for (int nb = 0; nb < 4; nb++){
    hipLaunchKernelGGL(k_dft, dim3(512), dim3(256), 0, stream, fr, FtabT, ft);
    hipLaunchKernelGGL(k_modemm, dim3(32,16), dim3(256), 0, stream,
                       ft, spec + (size_t)nb*1048576, oftb);
    hipLaunchKernelGGL(k_combine, dim3(16,256), dim3(256), 0, stream,
                       fr, oftb, cwb + nb*16384, conb + nb*128,
                       lng + nb*128, lnb + nb*128, GT);
  }
  hipLaunchKernelGGL(k_initout, dim3(64), dim3(256), 0, stream, x, pb2, (float*)d_out);
  hipLaunchKernelGGL(k_proj, dim3(16,256), dim3(256), 0, stream,
                     fr, w1b, pb1, w2b, (float*)d_out);
}

// Round 4
// 721.363 us; speedup vs baseline: 2.3474x; 1.1653x over previous
//
#include <hip/hip_runtime.h>
#include <math.h>

// NS=64 NG=3 W=128 L=1024 M=32 TD=64 CD=128 NB=4 B=256
// fr stored bf16 [b][c][l]. DFT/irfft as dense bf16 MFMA matmuls with
// precomputed transposed trig tables. LN + gelu epilogues in fp32.

typedef unsigned short u16;
typedef unsigned int u32;
typedef __attribute__((ext_vector_type(8))) short bf16x8;
typedef __attribute__((ext_vector_type(4))) float f32x4;

#define MFMA(a,b,c) __builtin_amdgcn_mfma_f32_16x16x32_bf16((a),(b),(c),0,0,0)

// fast tanh-GELU: gelu(x) = x * (1 - 1/(e^{2u}+1)), u = c1*(x + 0.044715 x^3)
// exp2 form: t = exp2(x*(a + b*x^2)), a = 2*c1/ln2, b = a*0.044715
__device__ __forceinline__ float gelu_f(float x){
  float x2 = x*x;
  float p  = __builtin_fmaf(0.10294323f, x2, 2.3022081f);
  float t  = __builtin_amdgcn_exp2f(x*p);
  float r  = __builtin_amdgcn_rcpf(t + 1.0f);
  return __builtin_fmaf(-x, r, x);
}
__device__ __forceinline__ u16 f2bf(float f){
  u32 u = __float_as_uint(f);
  u32 r = (u + 0x7FFFu + ((u>>16)&1u)) >> 16;
  return (u16)r;
}
__device__ __forceinline__ int SW3(int x){ return ((x&7) ^ ((x>>4)&7)); }  // 128/256B rows

// ---- tables: POS f32(128x1024); FtabT bf16(64q x 1024l); GT bf16(1024l x 64q);
//      cwb bf16(4x128x128); w1b; w2b; specr f32 [nb][k][i][o][2] ----
__global__ void k_tables(float* __restrict__ POS, u16* __restrict__ FtabT,
                         u16* __restrict__ GT, const float* __restrict__ conw,
                         u16* __restrict__ cwb, const float* __restrict__ pw1,
                         u16* __restrict__ w1b, const float* __restrict__ pw2,
                         u16* __restrict__ w2b, const float* __restrict__ spec,
                         float* __restrict__ specr){
  int idx = blockIdx.x*blockDim.x + threadIdx.x;
  if (idx < 128*1024){
    int i = idx >> 10, l = idx & 1023;
    int j = i >> 1;
    float d = exp2f(-(float)j*(13.287712379549449f/64.0f));
    float ang = (float)l*d;
    POS[idx] = (i&1) ? cosf(ang) : sinf(ang);
  }
  if (idx < 64*1024){
    int q = idx >> 10, l = idx & 1023;
    int k = q >> 1;
    int m = (k*l) & 1023;
    float s, c;
    sincospif((float)m*(1.0f/512.0f), &s, &c);
    FtabT[q*1024 + l] = f2bf((q&1) ? -s : c);
  }
  if (idx < 64*1024){
    int l = idx >> 6, q = idx & 63;
    int k = q >> 1;
    int m = (k*l) & 1023;
    float s, c;
    sincospif((float)m*(1.0f/512.0f), &s, &c);
    float sc = (k==0) ? (1.0f/1024.0f) : (2.0f/1024.0f);
    float v = (q&1) ? ((k==0) ? 0.0f : -sc*s) : sc*c;
    GT[l*64 + q] = f2bf(v);
  }
  if (idx < 4*128*128) cwb[idx] = f2bf(conw[idx]);
  if (idx < 64*128)    w1b[idx] = f2bf(pw1[idx]);
  if (idx < 64*64)     w2b[idx] = f2bf(pw2[idx]);
  if (idx < 4*128*128*8){
    int kq = idx & 7, o = (idx>>3)&127, i = (idx>>10)&127, nb = idx>>17;
    const float* s = spec + (((size_t)(nb*128+i)*128 + o)*32 + kq*4)*2;
    float4 v0 = *(const float4*)s;
    float4 v1 = *(const float4*)(s+4);
    float* d = specr + (size_t)nb*1048576 + i*256 + o*2;
    *(float2*)(d + (size_t)(kq*4+0)*32768) = make_float2(v0.x, v0.y);
    *(float2*)(d + (size_t)(kq*4+1)*32768) = make_float2(v0.z, v0.w);
    *(float2*)(d + (size_t)(kq*4+2)*32768) = make_float2(v1.x, v1.y);
    *(float2*)(d + (size_t)(kq*4+3)*32768) = make_float2(v1.z, v1.w);
  }
}

// ---- conditioning MLPs -> lifted (256x128) f32 ----
__global__ __launch_bounds__(128) void k_cond(const float* __restrict__ x,
    const float* __restrict__ ts,
    const float* __restrict__ w1, const float* __restrict__ b1,
    const float* __restrict__ w2, const float* __restrict__ b2,
    const float* __restrict__ lw, const float* __restrict__ lb,
    float* __restrict__ lifted){
  const int b = blockIdx.x, t = threadIdx.x;
  __shared__ float sp[64], cin[68], h[128], cond[128];
  const float* xr = x + b*68;
  if (t < 64) sp[t] = xr[t];
  if (t < 3)  cin[t] = xr[64+t];
  if (t >= 64 && t < 96){
    int j = t - 64;
    float tt = xr[67]*ts[0];
    float invf = exp2f(-(float)j*(13.287712379549449f/31.0f));
    float ang = tt*invf;
    cin[3+j]  = sinf(ang);
    cin[35+j] = cosf(ang);
  }
  __syncthreads();
  float acc = b1[t];
  for (int k = 0; k < 67; k++) acc += cin[k]*w1[t*67+k];
  h[t] = gelu_f(acc);
  __syncthreads();
  acc = b2[t];
  for (int k = 0; k < 128; k++) acc += h[k]*w2[t*128+k];
  cond[t] = acc;
  __syncthreads();
  acc = lb[t];
  const float* lwr = lw + t*192;
  for (int k = 0; k < 64; k++)  acc += sp[k]*lwr[k];
  for (int k = 0; k < 128; k++) acc += cond[k]*lwr[64+k];
  lifted[b*128 + t] = gelu_f(acc);
}

// ---- fr init (bf16): fr[b,c,l] = lifted[b,c] + POS[c,l] ----
__global__ __launch_bounds__(256) void k_frinit(const float* __restrict__ lifted,
    const float* __restrict__ POS, u16* __restrict__ fr){
  size_t idx = (size_t)blockIdx.x*256 + threadIdx.x;
  size_t e = idx*8;
  int bi = (int)(e >> 10);
  int l  = (int)(e & 1023);
  float lf = lifted[bi];
  const float* p = POS + (size_t)(bi & 127)*1024 + l;
  float4 p0 = *(const float4*)p;
  float4 p1 = *(const float4*)(p+4);
  u32 o0 = (u32)f2bf(lf+p0.x) | ((u32)f2bf(lf+p0.y)<<16);
  u32 o1 = (u32)f2bf(lf+p0.z) | ((u32)f2bf(lf+p0.w)<<16);
  u32 o2 = (u32)f2bf(lf+p1.x) | ((u32)f2bf(lf+p1.y)<<16);
  u32 o3 = (u32)f2bf(lf+p1.z) | ((u32)f2bf(lf+p1.w)<<16);
  *(uint4*)(fr + e) = make_uint4(o0,o1,o2,o3);
}

// ---- DFT: ft2[h](32768x64 f32) = fr(32768x512 bf16 half) @ FtabT-half ----
// No LDS; A-fragments straight from L2-resident FtabT. grid (512, 2).
__global__ __launch_bounds__(256) void k_dft(const u16* __restrict__ fr,
    const u16* __restrict__ FtabT, float* __restrict__ ft2){
  const int t = threadIdx.x, w = t >> 6, lane = t & 63;
  const int nlo = lane & 15, kg = lane >> 4;
  const int row0 = blockIdx.x * 64;
  const int h = blockIdx.y;
  const u16* frow  = fr + (size_t)(row0 + w*16 + nlo)*1024 + h*512;
  const u16* fbase = FtabT + h*512;
  f32x4 acc[4] = {};
  #pragma unroll 4
  for (int ks = 0; ks < 16; ++ks){
    bf16x8 b = *(const bf16x8*)(frow + ks*32 + kg*8);
    #pragma unroll
    for (int mf = 0; mf < 4; ++mf){
      bf16x8 a = *(const bf16x8*)(fbase + (size_t)(mf*16+nlo)*1024 + ks*32 + kg*8);
      acc[mf] = MFMA(a, b, acc[mf]);
    }
  }
  float* dst = ft2 + (size_t)h*2097152 + (size_t)(row0 + w*16 + nlo)*64;
  #pragma unroll
  for (int mf = 0; mf < 4; ++mf)
    *(float4*)(dst + mf*16 + kg*4) =
        make_float4(acc[mf][0], acc[mf][1], acc[mf][2], acc[mf][3]);
}

// ---- mode mix (fp32 VALU, coalesced specr), writes oft bf16 [b][o][64q] ----
__global__ __launch_bounds__(256) void k_modemm(const float* __restrict__ ft2,
    const float* __restrict__ specr, u16* __restrict__ oftb){
  const int k = blockIdx.x;            // 0..31
  const int b0 = blockIdx.y*8;         // 8 b per block
  const int t = threadIdx.x;
  __shared__ float fA[128][16];        // [i][b*2 + reim]
  {
    const int bl = t & 7, i0 = (t>>3)*4;
    #pragma unroll
    for (int ii = 0; ii < 4; ii++){
      int i = i0 + ii;
      size_t off = ((size_t)(b0+bl)*128 + i)*64 + 2*k;
      float2 v0 = *(const float2*)(ft2 + off);
      float2 v1 = *(const float2*)(ft2 + 2097152 + off);
      fA[i][bl*2]   = v0.x + v1.x;
      fA[i][bl*2+1] = v0.y + v1.y;
    }
  }
  __syncthreads();
  const int o = t & 127, bh = t >> 7;
  const float* sp = specr + (size_t)k*32768 + o*2;
  float accre[4] = {}, accim[4] = {};
  #pragma unroll 4
  for (int i = 0; i < 128; i++){
    float2 wv = *(const float2*)(sp + i*256);
    #pragma unroll
    for (int j = 0; j < 4; j++){
      float2 a = *(const float2*)&fA[i][(bh*4+j)*2];
      accre[j] += a.x*wv.x - a.y*wv.y;
      accim[j] += a.x*wv.y + a.y*wv.x;
    }
  }
  #pragma unroll
  for (int j = 0; j < 4; j++){
    u32 pk = (u32)f2bf(accre[j]) | ((u32)f2bf(accim[j])<<16);
    *(u32*)(oftb + ((size_t)(b0+bh*4+j)*128 + o)*64 + 2*k) = pk;
  }
}

// ---- combine: y = irfft(oft) + conv(fr) + cb; LN over o; gelu; fr in-place ----
// grid (16 ltiles, 256 b), 256 thr = 4 waves. D[l][o]: wave w: o-range w*32.
__global__ __launch_bounds__(256) void k_combine(u16* __restrict__ fr,
    const u16* __restrict__ oftb, const u16* __restrict__ cwb,
    const float* __restrict__ cb, const float* __restrict__ g,
    const float* __restrict__ bt, const u16* __restrict__ GT){
  const int l0 = blockIdx.x*64, b = blockIdx.y;
  const int t = threadIdx.x, w = t >> 6, lane = t & 63;
  const int nlo = lane & 15, kg = lane >> 4;
  __shared__ char smem[27136];
  u16* frT = (u16*)smem;                 // [64l][128c] 16KB (256B rows)
  u16* GTs = (u16*)(smem + 16384);       // [64l][64q]  8KB (128B rows)
  u16* ys  = (u16*)smem;                 // [128o][64l] 16KB, aliases frT
  float* red   = (float*)(smem + 24576); // [4][64][2]
  float* stats = (float*)(smem + 26624); // [64][2]

  // stage GT tile (swizzle on LDS write)
  #pragma unroll
  for (int r = 0; r < 2; ++r){
    int idx = r*256 + t;
    int l = idx >> 3, c8 = idx & 7;
    uint4 v = *(const uint4*)((const char*)GT + (size_t)(l0+l)*128 + c8*16);
    *(uint4*)((char*)GTs + l*128 + ((c8 ^ SW3(l))*16)) = v;
  }
  // transpose-stage fr tile -> frT[l][c]
  {
    int p = t >> 2, q2 = t & 3;            // c-pair 0..63, l-quarter
    const u16* r0 = fr + ((size_t)b*128 + 2*p)*1024 + l0 + q2*16;
    uint4 A0 = *(const uint4*)r0;
    uint4 A1 = *(const uint4*)(r0 + 8);
    uint4 B0 = *(const uint4*)(r0 + 1024);
    uint4 B1 = *(const uint4*)(r0 + 1032);
    u32 wa[8] = {A0.x,A0.y,A0.z,A0.w,A1.x,A1.y,A1.z,A1.w};
    u32 wb[8] = {B0.x,B0.y,B0.z,B0.w,B1.x,B1.y,B1.z,B1.w};
    #pragma unroll
    for (int j = 0; j < 16; ++j){
      u32 ua = wa[j>>1], ub = wb[j>>1];
      u32 out = (j&1) ? ((ua>>16) | (ub & 0xffff0000u))
                      : ((ua & 0xffffu) | (ub<<16));
      int l = q2*16 + j;
      *(u32*)((char*)frT + l*256 + (((p>>2) ^ SW3(l))*16) + (p&3)*4) = out;
    }
  }
  __syncthreads();

  f32x4 acc[4][2] = {};
  // K-part 1: irfft basis (q = 0..63)
  #pragma unroll
  for (int ki = 0; ki < 2; ++ki){
    int q0 = ki*32;
    bf16x8 bfr[2];
    #pragma unroll
    for (int nf = 0; nf < 2; ++nf){
      int o = w*32 + nf*16 + nlo;
      bfr[nf] = *(const bf16x8*)(oftb + ((size_t)b*128 + o)*64 + q0 + kg*8);
    }
    #pragma unroll
    for (int mf = 0; mf < 4; ++mf){
      int l = mf*16 + nlo;
      bf16x8 af = *(const bf16x8*)((const char*)GTs + l*128 + (((q0/8 + kg) ^ SW3(l))*16));
      acc[mf][0] = MFMA(af, bfr[0], acc[mf][0]);
      acc[mf][1] = MFMA(af, bfr[1], acc[mf][1]);
    }
  }
  // K-part 2: conv (c = 0..127)
  #pragma unroll
  for (int ki = 0; ki < 4; ++ki){
    int c0 = ki*32;
    bf16x8 bfr[2];
    #pragma unroll
    for (int nf = 0; nf < 2; ++nf){
      int o = w*32 + nf*16 + nlo;
      bfr[nf] = *(const bf16x8*)(cwb + o*128 + c0 + kg*8);
    }
    #pragma unroll
    for (int mf = 0; mf < 4; ++mf){
      int l = mf*16 + nlo;
      bf16x8 af = *(const bf16x8*)((const char*)frT + l*256 + (((c0/8 + kg) ^ SW3(l))*16));
      acc[mf][0] = MFMA(af, bfr[0], acc[mf][0]);
      acc[mf][1] = MFMA(af, bfr[1], acc[mf][1]);
    }
  }

  // bias + LN stats
  float cbv[2], gv[2], btv[2];
  #pragma unroll
  for (int nf = 0; nf < 2; ++nf){
    int o = w*32 + nf*16 + nlo;
    cbv[nf] = cb[o]; gv[nf] = g[o]; btv[nf] = bt[o];
  }
  #pragma unroll
  for (int mf = 0; mf < 4; ++mf)
    #pragma unroll
    for (int nf = 0; nf < 2; ++nf)
      #pragma unroll
      for (int r = 0; r < 4; ++r)
        acc[mf][nf][r] += cbv[nf];

  float s[4][4], s2[4][4];
  #pragma unroll
  for (int mf = 0; mf < 4; ++mf)
    #pragma unroll
    for (int r = 0; r < 4; ++r){
      float a0 = acc[mf][0][r], a1 = acc[mf][1][r];
      s[mf][r] = a0 + a1;
      s2[mf][r] = a0*a0 + a1*a1;
    }
  #pragma unroll
  for (int m = 1; m <= 8; m <<= 1){
    #pragma unroll
    for (int mf = 0; mf < 4; ++mf)
      #pragma unroll
      for (int r = 0; r < 4; ++r){
        s[mf][r]  += __shfl_xor(s[mf][r], m);
        s2[mf][r] += __shfl_xor(s2[mf][r], m);
      }
  }
  if (nlo == 0){
    #pragma unroll
    for (int mf = 0; mf < 4; ++mf)
      #pragma unroll
      for (int r = 0; r < 4; ++r){
        int l = mf*16 + kg*4 + r;
        red[(w*64 + l)*2 + 0] = s[mf][r];
        red[(w*64 + l)*2 + 1] = s2[mf][r];
      }
  }
  __syncthreads();
  if (t < 64){
    float ss  = red[t*2] + red[(64+t)*2] + red[(128+t)*2] + red[(192+t)*2];
    float ss2 = red[t*2+1] + red[(64+t)*2+1] + red[(128+t)*2+1] + red[(192+t)*2+1];
    float mu = ss*(1.0f/128.0f);
    float var = ss2*(1.0f/128.0f) - mu*mu;
    stats[t*2+0] = mu;
    stats[t*2+1] = rsqrtf(var + 1e-5f);
  }
  __syncthreads();

  // normalize + gelu + pack to ys[o][l] (aliases frT — safe after barrier)
  #pragma unroll
  for (int mf = 0; mf < 4; ++mf){
    float2 st[4];
    #pragma unroll
    for (int r = 0; r < 4; ++r)
      st[r] = *(const float2*)&stats[(mf*16 + kg*4 + r)*2];
    #pragma unroll
    for (int nf = 0; nf < 2; ++nf){
      float vs[4];
      #pragma unroll
      for (int r = 0; r < 4; ++r){
        float v = (acc[mf][nf][r] - st[r].x)*st[r].y*gv[nf] + btv[nf];
        vs[r] = gelu_f(v);
      }
      u32 u01 = (u32)f2bf(vs[0]) | ((u32)f2bf(vs[1])<<16);
      u32 u23 = (u32)f2bf(vs[2]) | ((u32)f2bf(vs[3])<<16);
      int o = w*32 + nf*16 + nlo;
      int byteoff = o*128 + (((mf*2 + (kg>>1)) ^ SW3(o))*16) + (kg&1)*8;
      *(uint2*)((char*)ys + byteoff) = make_uint2(u01, u23);
    }
  }
  __syncthreads();
  // coalesced fr writeback
  {
    int o = t >> 1, half = t & 1;
    const char* base = (const char*)ys + o*128;
    u16* dst = fr + ((size_t)b*128 + o)*1024 + l0 + half*32;
    #pragma unroll
    for (int j = 0; j < 4; ++j){
      int chunk = half*4 + j;
      uint4 v = *(const uint4*)(base + ((chunk ^ SW3(o))*16));
      *(uint4*)(dst + j*8) = v;
    }
  }
}

// ---- out init: out = sp + proj_b2 ----
__global__ void k_initout(const float* __restrict__ x,
    const float* __restrict__ b2, float* __restrict__ out){
  int idx = blockIdx.x*256 + threadIdx.x;
  if (idx < 256*64){
    int b = idx >> 6, o = idx & 63;
    out[idx] = x[b*68 + o] + b2[o];
  }
}

// ---- projection (MFMA) + mean over L ----
__global__ __launch_bounds__(256) void k_proj(const u16* __restrict__ fr,
    const u16* __restrict__ w1b, const float* __restrict__ pb1,
    const u16* __restrict__ w2b, float* __restrict__ out){
  const int l0 = blockIdx.x*64, b = blockIdx.y;
  const int t = threadIdx.x, w = t >> 6, lane = t & 63;
  const int nlo = lane & 15, kg = lane >> 4;
  __shared__ u16 frT[64*128];   // 16KB [l][c] swizzled
  __shared__ u16 h2T[64*64];    // 8KB  [l][h] swizzled

  {
    int p = t >> 2, q2 = t & 3;
    const u16* r0 = fr + ((size_t)b*128 + 2*p)*1024 + l0 + q2*16;
    uint4 A0 = *(const uint4*)r0;
    uint4 A1 = *(const uint4*)(r0 + 8);
    uint4 B0 = *(const uint4*)(r0 + 1024);
    uint4 B1 = *(const uint4*)(r0 + 1032);
    u32 wa[8] = {A0.x,A0.y,A0.z,A0.w,A1.x,A1.y,A1.z,A1.w};
    u32 wb[8] = {B0.x,B0.y,B0.z,B0.w,B1.x,B1.y,B1.z,B1.w};
    #pragma unroll
    for (int j = 0; j < 16; ++j){
      u32 ua = wa[j>>1], ub = wb[j>>1];
      u32 o32 = (j&1) ? ((ua>>16) | (ub & 0xffff0000u))
                      : ((ua & 0xffffu) | (ub<<16));
      int l = q2*16 + j;
      *(u32*)((char*)frT + l*256 + (((p>>2) ^ SW3(l))*16) + (p&3)*4) = o32;
    }
  }
  __syncthreads();

  // GEMM1: h2[l][h] = gelu(fr^T @ w1^T + b1), wave w: h-range w*16
  f32x4 acc1[4] = {};
  #pragma unroll
  for (int ki = 0; ki < 4; ++ki){
    int c0 = ki*32;
    bf16x8 bfr = *(const bf16x8*)(w1b + (w*16 + nlo)*128 + c0 + kg*8);
    #pragma unroll
    for (int mf = 0; mf < 4; ++mf){
      int l = mf*16 + nlo;
      bf16x8 af = *(const bf16x8*)((const char*)frT + l*256 + (((c0/8 + kg) ^ SW3(l))*16));
      acc1[mf] = MFMA(af, bfr, acc1[mf]);
    }
  }
  float b1v = pb1[w*16 + nlo];
  #pragma unroll
  for (int mf = 0; mf < 4; ++mf){
    float vs[4];
    #pragma unroll
    for (int r = 0; r < 4; ++r) vs[r] = gelu_f(acc1[mf][r] + b1v);
    u32 w01 = (u32)f2bf(vs[0]) | ((u32)f2bf(vs[1])<<16);
    u32 w23 = (u32)f2bf(vs[2]) | ((u32)f2bf(vs[3])<<16);
    u32 p01 = __shfl_xor(w01, 1), p23 = __shfl_xor(w23, 1);
    int h = w*16 + nlo, hp = h >> 1;
    u32 outA, outB; int rA, rB;
    if (!(h & 1)){
      outA = (w01 & 0xffffu) | (p01 << 16); rA = 0;
      outB = (w01 >> 16) | (p01 & 0xffff0000u); rB = 1;
    } else {
      outA = (p23 & 0xffffu) | (w23 << 16); rA = 2;
      outB = (p23 >> 16) | (w23 & 0xffff0000u); rB = 3;
    }
    int lA = mf*16 + kg*4 + rA, lB = mf*16 + kg*4 + rB;
    *(u32*)((char*)h2T + lA*128 + (((hp>>2) ^ SW3(lA))*16) + (hp&3)*4) = outA;
    *(u32*)((char*)h2T + lB*128 + (((hp>>2) ^ SW3(lB))*16) + (hp&3)*4) = outB;
  }
  __syncthreads();

  // GEMM2: out[l][o] = h2 @ w2^T, wave w: o-range w*16; then mean over l
  f32x4 acc2[4] = {};
  #pragma unroll
  for (int ki = 0; ki < 2; ++ki){
    int h0 = ki*32;
    bf16x8 bfr = *(const bf16x8*)(w2b + (w*16 + nlo)*64 + h0 + kg*8);
    #pragma unroll
    for (int mf = 0; mf < 4; ++mf){
      int l = mf*16 + nlo;
      bf16x8 af = *(const bf16x8*)((const char*)h2T + l*128 + (((h0/8 + kg) ^ SW3(l))*16));
      acc2[mf] = MFMA(af, bfr, acc2[mf]);
    }
  }
  float ssum = 0.0f;
  #pragma unroll
  for (int mf = 0; mf < 4; ++mf)
    #pragma unroll
    for (int r = 0; r < 4; ++r) ssum += acc2[mf][r];
  ssum += __shfl_xor(ssum, 16);
  ssum += __shfl_xor(ssum, 32);
  if (kg == 0) atomicAdd(out + (size_t)b*64 + w*16 + nlo, ssum*(1.0f/1024.0f));
}

extern "C" void kernel_launch(void* const* d_in, const int* in_sizes, int n_in,
                              void* d_out, int out_size, void* d_ws, size_t ws_size,
                              hipStream_t stream){
  const float* x    = (const float*)d_in[0];
  const float* ts   = (const float*)d_in[1];
  const float* cw1  = (const float*)d_in[2];
  const float* cb1  = (const float*)d_in[3];
  const float* cw2  = (const float*)d_in[4];
  const float* cb2  = (const float*)d_in[5];
  const float* lw   = (const float*)d_in[6];
  const float* lb   = (const float*)d_in[7];
  const float* spec = (const float*)d_in[8];
  const float* conw = (const float*)d_in[9];
  const float* conb = (const float*)d_in[10];
  const float* lng  = (const float*)d_in[11];
  const float* lnb  = (const float*)d_in[12];
  const float* pw1  = (const float*)d_in[13];
  const float* pb1  = (const float*)d_in[14];
  const float* pw2  = (const float*)d_in[15];
  const float* pb2  = (const float*)d_in[16];

  char* W = (char*)d_ws;
  u16*   fr     = (u16*)  (W);                    // 67,108,864 B
  float* ft2    = (float*)(W + 67108864);         // 16,777,216 B (2 halves)
  u16*   oftb   = (u16*)  (W + 83886080);         //  4,194,304 B
  float* lifted = (float*)(W + 88080384);         //    131,072 B
  float* POS    = (float*)(W + 88211456);         //    524,288 B
  u16*   FtabT  = (u16*)  (W + 88735744);         //    131,072 B
  u16*   GT     = (u16*)  (W + 88866816);         //    131,072 B
  u16*   cwb    = (u16*)  (W + 88997888);         //    131,072 B
  u16*   w1b    = (u16*)  (W + 89128960);         //     16,384 B
  u16*   w2b    = (u16*)  (W + 89145344);         //      8,192 B
  float* specr  = (float*)(W + 89153536);         // 16,777,216 B (~106 MB tot)

  hipLaunchKernelGGL(k_tables, dim3(2048), dim3(256), 0, stream,
                     POS, FtabT, GT, conw, cwb, pw1, w1b, pw2, w2b, spec, specr);
  hipLaunchKernelGGL(k_cond, dim3(256), dim3(128), 0, stream,
                     x, ts, cw1, cb1, cw2, cb2, lw, lb, lifted);
  hipLaunchKernelGGL(k_frinit, dim3(16384), dim3(256), 0, stream, lifted, POS, fr);
  for (int nb = 0; nb < 4; nb++){
    hipLaunchKernelGGL(k_dft, dim3(512,2), dim3(256), 0, stream, fr, FtabT, ft2);
    hipLaunchKernelGGL(k_modemm, dim3(32,32), dim3(256), 0, stream,
                       ft2, specr + (size_t)nb*1048576, oftb);
    hipLaunchKernelGGL(k_combine, dim3(16,256), dim3(256), 0, stream,
                       fr, oftb, cwb + nb*16384, conb + nb*128,
                       lng + nb*128, lnb + nb*128, GT);
  }
  hipLaunchKernelGGL(k_initout, dim3(64), dim3(256), 0, stream, x, pb2, (float*)d_out);
  hipLaunchKernelGGL(k_proj, dim3(16,256), dim3(256), 0, stream,
                     fr, w1b, pb1, w2b, (float*)d_out);
}